// Round 14
// baseline (49.461 us; speedup 1.0000x reference)
//
#include <hip/hip_runtime.h>
#include <hip/hip_bf16.h>
#include <stdint.h>

#define NROWS 8192
#define DDIM  128
#define NCHUNK 16            // column chunks (partial-sum slots) for down
#define ROWS_PER_BLOCK 128   // 4 waves x 32 rows
#define COLS_PER_BLOCK 512   // NROWS / NCHUNK
#define GROUP_COLS 64        // cols staged per LDS buffer
#define GROUP_BYTES (GROUP_COLS * DDIM)       // fp8: 8192 B
#define NGROUPS (COLS_PER_BLOCK / GROUP_COLS) // 8
#define NCLASS 100
#define MAXC 192             // class panel capacity (mean 82, +12 sigma)

typedef __attribute__((ext_vector_type(4))) float f32x4;
typedef __attribute__((ext_vector_type(4))) int   i32x4;
typedef long f8x8;           // 8 fp8 elements = 8 bytes = 2 VGPRs

__device__ __forceinline__ void load_lds16(const void* g, void* l) {
    __builtin_amdgcn_global_load_lds(
        (const __attribute__((address_space(1))) void*)g,
        (__attribute__((address_space(3))) void*)l, 16, 0, 0);
}

// (1/tau) * log2(e); q is pre-scaled by sqrt of this so exp2(acc) = e^{s/tau}.
#define SCALE 14.426950408889634f
#define E10   22026.465794806718f   // exp(1/tau) exact diagonal term

// ---------- Kernel 1: row-normalize fp32 -> scaled fp8, emit ||q||^2 -----
__global__ __launch_bounds__(256) void normalize_kernel(
    const float* __restrict__ x, unsigned short* __restrict__ q16,
    float* __restrict__ dsq)
{
    int wave = threadIdx.x >> 6;
    int lane = threadIdx.x & 63;
    int row  = blockIdx.x * 4 + wave;
    const float2* xr = (const float2*)(x + (size_t)row * DDIM);
    float2 v = xr[lane];
    float ss = v.x * v.x + v.y * v.y;
    #pragma unroll
    for (int off = 1; off < 64; off <<= 1)
        ss += __shfl_xor(ss, off, 64);
    float rn = sqrtf(SCALE / ss);
    int pk = __builtin_amdgcn_cvt_pk_fp8_f32(v.x * rn, v.y * rn, 0, false);
    q16[(size_t)row * 64 + lane] = (unsigned short)(pk & 0xffff);
    // exact quantized self-energy (matches what the MFMA diagonal computes)
    float d0 = __builtin_amdgcn_cvt_f32_fp8(pk, 0);
    float d1 = __builtin_amdgcn_cvt_f32_fp8(pk, 1);
    float sq = d0 * d0 + d1 * d1;
    #pragma unroll
    for (int off = 1; off < 64; off <<= 1)
        sq += __shfl_xor(sq, off, 64);
    if (lane == 0) dsq[row] = sq;
}

// ---------- Kernel 2: class histogram + prefix + rank (1 block) ----------
__global__ __launch_bounds__(1024) void hist_kernel(
    const int* __restrict__ y, int* __restrict__ class_start,
    int* __restrict__ rowmap)
{
    __shared__ int bins[NCLASS];
    __shared__ int base[NCLASS + 1];
    const int tid = threadIdx.x;
    if (tid < NCLASS) bins[tid] = 0;
    __syncthreads();
    #pragma unroll
    for (int k = 0; k < 8; ++k)
        atomicAdd(&bins[y[tid + k * 1024]], 1);
    __syncthreads();
    if (tid == 0) {
        int run = 0;
        for (int c = 0; c < NCLASS; ++c) { base[c] = run; run += bins[c]; }
        base[NCLASS] = run;
    }
    __syncthreads();
    if (tid <= NCLASS) class_start[tid] = base[tid];
    if (tid < NCLASS)  bins[tid] = base[tid];   // reuse as cursors
    __syncthreads();
    #pragma unroll
    for (int k = 0; k < 8; ++k) {
        int i = tid + k * 1024;
        int g = atomicAdd(&bins[y[i]], 1);
        rowmap[g] = i;
    }
}

// ---------- Kernel 3: gather-permute q16 -> class-sorted qsorted ---------
__global__ __launch_bounds__(256) void permute_kernel(
    const unsigned short* __restrict__ q16, const int* __restrict__ rowmap,
    unsigned short* __restrict__ qsorted)
{
    int t = blockIdx.x * 256 + threadIdx.x;   // 65536 threads x 16 B
    int g = t >> 3, part = t & 7;
    int i = rowmap[g];
    i32x4 v = *(const i32x4*)((const char*)q16 + (size_t)i * 128 + part * 16);
    *(i32x4*)((char*)qsorted + (size_t)g * 128 + part * 16) = v;
}

// ---------- Kernel 4: fp8 QQ^T + exp2 -> row-sums (DOWN only) ------------
// Exactly R6's proven structure minus all label/top logic: hot loop is
// ds_read -> MFMA -> exp2 -> add. grid = 64 row-blocks x 16 col-chunks,
// 4 waves/block, 64-col double-buffered groups, pre-swizzled staging
// (XOR byte bits 4-6 keyed by col&7; 16B granule untouched, T21-safe).
__global__ __launch_bounds__(256, 4) void sim_kernel(
    const unsigned short* __restrict__ q16, float* __restrict__ downp)
{
    __shared__ char smem[2 * GROUP_BYTES];

    const int bid  = blockIdx.x;
    const int iblk = bid >> 4;
    const int h    = bid & 15;
    const int tid  = threadIdx.x;
    const int lane = tid & 63;
    const int wave = tid >> 6;
    const int lrow = lane & 15;
    const int lhi  = lane >> 4;

    const char* qb = (const char*)q16;
    const int rbase = iblk * ROWS_PER_BLOCK + wave * 32;
    const int jbase = h * COLS_PER_BLOCK;

    // A fragments: 2 row-tiles x 4 K-slices, 8B each (16 VGPRs total).
    f8x8 afrag[2][4];
    #pragma unroll
    for (int t = 0; t < 2; ++t)
        #pragma unroll
        for (int ks = 0; ks < 4; ++ks)
            afrag[t][ks] = *(const f8x8*)(qb +
                (size_t)(rbase + t * 16 + lrow) * DDIM + ks * 32 + lhi * 8);

    // Keep-alive pins: block the R1/R5/R10/R11 remat/spill pathology.
    #pragma unroll
    for (int t = 0; t < 2; ++t)
        #pragma unroll
        for (int ks = 0; ks < 4; ++ks)
            asm volatile("" : "+v"(afrag[t][ks]));

    float down[2][4] = {{0.f,0.f,0.f,0.f},{0.f,0.f,0.f,0.f}};

    auto stage = [&](int buf, int g) {
        const int jstart = jbase + g * GROUP_COLS;
        #pragma unroll
        for (int p = 0; p < 2; ++p) {
            int phys = p * 4096 + tid * 16;
            int col  = phys >> 7;
            int L    = phys ^ ((col & 7) << 4);
            const char* src = qb + (size_t)(jstart + col) * DDIM + (L & 127);
            load_lds16(src, smem + buf * GROUP_BYTES + phys);
        }
    };

    stage(0, 0);
    __syncthreads();

    for (int g = 0; g < NGROUPS; ++g) {
        if (g + 1 < NGROUPS) stage((g + 1) & 1, g + 1);

        const char* lbuf = smem + (g & 1) * GROUP_BYTES;

        #pragma unroll
        for (int jt = 0; jt < GROUP_COLS / 16; ++jt) {
            const int cg = jt * 16 + lrow;
            f8x8 bfrag[4];
            #pragma unroll
            for (int ks = 0; ks < 4; ++ks) {
                int off = cg * DDIM + ((ks * 32 + lhi * 8) ^ ((cg & 7) << 4));
                bfrag[ks] = *(const f8x8*)(lbuf + off);
            }
            #pragma unroll
            for (int t = 0; t < 2; ++t) {
                f32x4 acc = {0.f, 0.f, 0.f, 0.f};
                #pragma unroll
                for (int ks = 0; ks < 4; ++ks)
                    acc = __builtin_amdgcn_mfma_f32_16x16x32_fp8_fp8(
                        afrag[t][ks], bfrag[ks], acc, 0, 0, 0);
                #pragma unroll
                for (int r = 0; r < 4; ++r)
                    down[t][r] += __builtin_amdgcn_exp2f(acc[r]);
            }
        }
        __syncthreads();
    }

    #pragma unroll
    for (int m = 1; m < 16; m <<= 1)
        #pragma unroll
        for (int t = 0; t < 2; ++t)
            #pragma unroll
            for (int r = 0; r < 4; ++r)
                down[t][r] += __shfl_xor(down[t][r], m, 64);

    if (lrow == 0) {
        #pragma unroll
        for (int t = 0; t < 2; ++t)
            #pragma unroll
            for (int r = 0; r < 4; ++r) {
                int row = rbase + t * 16 + lhi * 4 + r;
                downp[h * NROWS + row] = down[t][r];
            }
    }
}

// ---------- Kernel 5: TOP via per-class diagonal block (100 blocks) ------
// Class c: rows [s,e) of qsorted are all label c. top for those rows =
// row-sums of exp2(S) over the L x L class block (~82 avg). Panel staged
// in LDS with the same proven swizzle; 16x16 fp8 MFMA; cols >= L dropped
// via bitwise select (NaN/inf-safe); rows >= L not written.
__global__ __launch_bounds__(256) void top_kernel(
    const unsigned short* __restrict__ qsorted,
    const int* __restrict__ class_start, const int* __restrict__ rowmap,
    float* __restrict__ topO)
{
    __shared__ char panel[MAXC * DDIM];   // 24576 B

    const int c = blockIdx.x;
    const int s = class_start[c];
    const int L = class_start[c + 1] - s;
    if (L <= 0) return;

    const int tid  = threadIdx.x;
    const int lane = tid & 63;
    const int wave = tid >> 6;
    const int lrow = lane & 15;
    const int lhi  = lane >> 4;
    const char* qb = (const char*)qsorted;

    const int nbytes = L * DDIM;
    for (int off = tid * 16; off < nbytes; off += 256 * 16) {
        int col = off >> 7;
        int Lo  = off ^ ((col & 7) << 4);
        load_lds16(qb + (size_t)(s + col) * DDIM + (Lo & 127), panel + off);
    }
    __syncthreads();

    const int nt = (L + 15) >> 4;
    for (int rt = wave; rt < nt; rt += 4) {
        const int ar = rt * 16 + lrow;
        f8x8 afrag[4];
        #pragma unroll
        for (int ks = 0; ks < 4; ++ks) {
            int off = ar * DDIM + ((ks * 32 + lhi * 8) ^ ((ar & 7) << 4));
            afrag[ks] = *(const f8x8*)(panel + off);
        }
        float tsum[4] = {0.f, 0.f, 0.f, 0.f};
        for (int ct = 0; ct < nt; ++ct) {
            const int cg = ct * 16 + lrow;
            f8x8 bfrag[4];
            #pragma unroll
            for (int ks = 0; ks < 4; ++ks) {
                int off = cg * DDIM + ((ks * 32 + lhi * 8) ^ ((cg & 7) << 4));
                bfrag[ks] = *(const f8x8*)(panel + off);
            }
            f32x4 acc = {0.f, 0.f, 0.f, 0.f};
            #pragma unroll
            for (int ks = 0; ks < 4; ++ks)
                acc = __builtin_amdgcn_mfma_f32_16x16x32_fp8_fp8(
                    afrag[ks], bfrag[ks], acc, 0, 0, 0);
            const bool colok = cg < L;
            #pragma unroll
            for (int r = 0; r < 4; ++r) {
                float ev = __builtin_amdgcn_exp2f(acc[r]);
                tsum[r] += colok ? ev : 0.0f;   // bitwise select, NaN-safe
            }
        }
        #pragma unroll
        for (int m = 1; m < 16; m <<= 1)
            #pragma unroll
            for (int r = 0; r < 4; ++r)
                tsum[r] += __shfl_xor(tsum[r], m, 64);
        if (lrow == 0) {
            #pragma unroll
            for (int r = 0; r < 4; ++r) {
                int rr = rt * 16 + lhi * 4 + r;
                if (rr < L) topO[rowmap[s + rr]] = tsum[r];
            }
        }
    }
}

// ---------- Kernel 6: per-row loss + block partials (32 x 256) -----------
__global__ __launch_bounds__(256) void loss_partial_kernel(
    const float* __restrict__ downp, const float* __restrict__ topO,
    const float* __restrict__ dsq, float* __restrict__ partial)
{
    __shared__ float sred[4];
    const int tid  = threadIdx.x;
    const int lane = tid & 63;
    const int wave = tid >> 6;
    const int r = blockIdx.x * 256 + tid;

    float d = 0.f;
    #pragma unroll
    for (int hh = 0; hh < NCHUNK; ++hh)
        d += downp[hh * NROWS + r];
    float t = topO[r];
    // replace quantized diagonal exp2(||q||^2) with exact e^{1/tau}
    float e2d = __builtin_amdgcn_exp2f(dsq[r]);
    t += E10 - e2d;
    d += E10 - e2d;
    float s = __logf(d) - __logf(t);
    #pragma unroll
    for (int off = 1; off < 64; off <<= 1)
        s += __shfl_xor(s, off, 64);
    if (lane == 0) sred[wave] = s;
    __syncthreads();
    if (tid == 0) partial[blockIdx.x] = sred[0] + sred[1] + sred[2] + sred[3];
}

// ---------- Kernel 7: final 32 -> scalar ---------------------------------
__global__ __launch_bounds__(64) void loss_final_kernel(
    const float* __restrict__ partial, float* __restrict__ out)
{
    const int lane = threadIdx.x;
    float s = (lane < 32) ? partial[lane] : 0.f;
    #pragma unroll
    for (int off = 1; off < 64; off <<= 1)
        s += __shfl_xor(s, off, 64);
    if (lane == 0) out[0] = s / (float)NROWS;
}

extern "C" void kernel_launch(void* const* d_in, const int* in_sizes, int n_in,
                              void* d_out, int out_size, void* d_ws, size_t ws_size,
                              hipStream_t stream)
{
    const float* x = (const float*)d_in[0];
    const int*   y = (const int*)d_in[1];
    float* out = (float*)d_out;

    char* ws = (char*)d_ws;
    unsigned short* q16     = (unsigned short*)ws;                   // 1 MB
    unsigned short* qsorted = (unsigned short*)(ws + (1 << 20));     // 1 MB
    float* downp       = (float*)(ws + (2 << 20));                   // 512 KB
    float* topO        = downp + NCHUNK * NROWS;                     // 32 KB
    float* dsq         = topO + NROWS;                               // 32 KB
    int*   rowmap      = (int*)(dsq + NROWS);                        // 32 KB
    int*   class_start = rowmap + NROWS;                             // 404 B
    float* partial     = (float*)(class_start + NCLASS + 4);         // 128 B

    normalize_kernel<<<NROWS / 4, 256, 0, stream>>>(x, q16, dsq);
    hist_kernel<<<1, 1024, 0, stream>>>(y, class_start, rowmap);
    permute_kernel<<<NROWS * 8 / 256, 256, 0, stream>>>(q16, rowmap, qsorted);
    sim_kernel<<<64 * NCHUNK, 256, 0, stream>>>(q16, downp);
    top_kernel<<<NCLASS, 256, 0, stream>>>(qsorted, class_start, rowmap, topO);
    loss_partial_kernel<<<NROWS / 256, 256, 0, stream>>>(downp, topO, dsq, partial);
    loss_final_kernel<<<1, 64, 0, stream>>>(partial, out);
}